// Round 2
// baseline (340.555 us; speedup 1.0000x reference)
//
#include <hip/hip_runtime.h>

// ---------------------------------------------------------------------------
// ConvCaps (EM routing): b=8, B=32, C=32, K=3, stride=2, Win=13, Wout=6, 3 iters
// x: (8, 544, 13, 13) f32   [pose 512ch = (q,r,o), act 32ch]
// W: (3,3,32,32,4,4) f32    [i,j,o,c,p,q]
// out: (8, 544, 6, 6) f32
// vote[d = p*4+r] = sum_q W[i,j,o,c,p,q] * pose[n,q,r,o,2x+i,2y+j]
// child index ch = ij*32 + o  (cheap bit decode; p_hat layout matches)
// p_hat layout: [spatial][ch][c]  -> coalesced estep stores
// ---------------------------------------------------------------------------

#define NCHILD 288
#define NPAIR  2654208        // 9216 parents * 288 children

// workspace layout (floats)
#define OFF_PHAT 0            // 2654208
#define OFF_D    2654208      // 43264 = 8*32*169
#define OFF_MU   2697472      // 9216*16
#define OFF_G    2844928      // 9216
#define OFF_E    2854144      // 43264
#define OFF_POST 2897408      // 692224 = 8*32*169*16
// total 3589632 floats = 14.36 MB

__device__ __forceinline__ float wred64(float v) {
#pragma unroll
  for (int m = 32; m >= 1; m >>= 1) v += __shfl_xor(v, m, 64);
  return v;
}

__device__ __forceinline__ void load16(const float* __restrict__ p, float* dst) {
  const float4* p4 = (const float4*)p;
  float4 a = p4[0], b = p4[1], c = p4[2], d = p4[3];
  dst[0]=a.x; dst[1]=a.y; dst[2]=a.z; dst[3]=a.w;
  dst[4]=b.x; dst[5]=b.y; dst[6]=b.z; dst[7]=b.w;
  dst[8]=c.x; dst[9]=c.y; dst[10]=c.z; dst[11]=c.w;
  dst[12]=d.x; dst[13]=d.y; dst[14]=d.z; dst[15]=d.w;
}

// transpose pose: x[n, (q*4+r)*32+o, pix] -> posT[((n*32+o)*169+pix)*16 + d]
__global__ __launch_bounds__(256) void prep_kernel(const float* __restrict__ x,
                                                   float* __restrict__ posT) {
  int tid = blockIdx.x * 256 + threadIdx.x;   // 692224 = 2704*256
  int pix = tid % 169; int t = tid / 169;
  int o = t & 31; t >>= 5;
  int d = t & 15; int n = t >> 4;
  float v = x[((size_t)n * 544 + d * 32 + o) * 169 + pix];
  posT[((size_t)(n * 32 + o) * 169 + pix) * 16 + d] = v;
}

// E = a / 1152  (uniform-Rp rhat for iteration 0)
__global__ __launch_bounds__(256) void e0_kernel(const float* __restrict__ x,
                                                 float* __restrict__ E) {
  int idx = blockIdx.x * 256 + threadIdx.x;   // 43264 = 169*256
  int n = idx / 5408; int r = idx - n * 5408; // r = o*169+pix
  E[idx] = x[(size_t)n * 91936 + 86528 + r] * (1.0f / 1152.0f);
}

// E = a / D  after each E-step
__global__ __launch_bounds__(256) void recip_kernel(const float* __restrict__ x,
                                                    const float* __restrict__ D,
                                                    float* __restrict__ E) {
  int idx = blockIdx.x * 256 + threadIdx.x;
  int n = idx / 5408; int r = idx - n * 5408;
  E[idx] = x[(size_t)n * 91936 + 86528 + r] / D[idx];
}

// M-step: block = 256 threads = 4 waves = 4 parents sharing one spatial (n,x,y).
// Pose patch (288 children x 16) and E patch staged in LDS.
// mode 0: rhat = E (uniform Rp);  mode 1: rhat = p_hat*E;  mode 2: same + write out
__global__ __launch_bounds__(256, 4) void mstep_kernel(
    const float* __restrict__ Wt, const float* __restrict__ posT,
    const float* __restrict__ p_hat, const float* __restrict__ E,
    float* __restrict__ mu_out, float* __restrict__ G_out,
    const float* __restrict__ beta_v, const float* __restrict__ beta_a,
    const float* __restrict__ lambda_, float* __restrict__ out, int mode) {
  __shared__ float sP[288 * 20];   // stride 20 floats: conflict-free b128
  __shared__ float sE[288];

  const int wave = threadIdx.x >> 6;
  const int lane = threadIdx.x & 63;
  const int pid = blockIdx.x * 4 + wave;
  const int c = pid & 31;
  const int spatial = pid >> 5;
  int t = spatial;
  const int y = t % 6; t /= 6;
  const int xx = t % 6;
  const int n = t / 6;

  // cooperative stage: 288 children * 4 float4 quads
  for (int task = threadIdx.x; task < 1152; task += 256) {
    int ch = task >> 2, q = task & 3;
    int o = ch & 31, ij = ch >> 5;
    int i = ij / 3, j = ij - i * 3;
    int row = 2 * xx + i, col = 2 * y + j;
    float4 v = *(const float4*)(posT +
        ((size_t)((n * 32 + o) * 169) + row * 13 + col) * 16 + q * 4);
    *(float4*)(sP + ch * 20 + q * 4) = v;
  }
  for (int task = threadIdx.x; task < 288; task += 256) {
    int o = task & 31, ij = task >> 5;
    int i = ij / 3, j = ij - i * 3;
    sE[task] = E[((n * 32 + o) * 13 + 2 * xx + i) * 13 + 2 * y + j];
  }
  __syncthreads();

  float sum_r = 0.f;
  float sv[16], sq[16];
#pragma unroll
  for (int d = 0; d < 16; ++d) { sv[d] = 0.f; sq[d] = 0.f; }

  const float* phb = p_hat + (size_t)spatial * 9216 + c;  // [(spatial*288+ch)*32+c]

#pragma unroll
  for (int k = 0; k < 5; ++k) {
    int ch = lane + 64 * k;
    const bool active = (ch < NCHILD);
    const int chm = active ? ch : 0;

    float P[16];
    load16(sP + chm * 20, P);
    float Wm[16];
    load16(Wt + (size_t)chm * 512 + c * 16, Wm);

    float rhat;
    if (mode == 0) rhat = sE[chm];
    else           rhat = phb[(size_t)chm * 32] * sE[chm];
    if (!active) rhat = 0.f;
    sum_r += rhat;
#pragma unroll
    for (int p = 0; p < 4; ++p)
#pragma unroll
      for (int r = 0; r < 4; ++r) {
        float v = Wm[p * 4 + 0] * P[0 + r] + Wm[p * 4 + 1] * P[4 + r] +
                  Wm[p * 4 + 2] * P[8 + r] + Wm[p * 4 + 3] * P[12 + r];
        sv[p * 4 + r] = fmaf(rhat, v, sv[p * 4 + r]);
        sq[p * 4 + r] = fmaf(rhat * v, v, sq[p * 4 + r]);
      }
  }

  sum_r = wred64(sum_r);
  const float inv_sr = 1.0f / sum_r;
  float mu[16], sig[16];
#pragma unroll
  for (int d = 0; d < 16; ++d) {
    float s1 = wred64(sv[d]);
    float s2 = wred64(sq[d]);
    float m = s1 * inv_sr;
    mu[d] = m;
    sig[d] = fmaxf(s2 * inv_sr - m * m, 1e-30f);
  }

  const float bv = beta_v[0], ba = beta_a[0], lam = lambda_[0];
  float lsum = 0.f;
#pragma unroll
  for (int d = 0; d < 16; ++d) lsum += __logf(sig[d]);
  const float cost = (16.f * bv + lsum) * sum_r;
  const float z = lam * (ba - cost);
  const float aout = 1.0f / (1.0f + __expf(-z));

  if (lane == 0) {
    if (mode == 2) {
      float* ob = out + (size_t)(n * 544 + c * 16) * 36 + xx * 6 + y;
#pragma unroll
      for (int d = 0; d < 16; ++d) ob[d * 36] = mu[d];
      out[(size_t)(n * 544 + 512 + c) * 36 + xx * 6 + y] = aout;
    } else {
      float* mb = mu_out + (size_t)pid * 16;
#pragma unroll
      for (int d = 0; d < 16; ++d) mb[d] = mu[d];
      const float S = lsum + 16.f * 1.8378770664093453f;  // + 16*log(2*pi)
      G_out[pid] = __logf(aout) - 0.5f * S;
    }
  }
}

// E-step: thread per (child, c). Block = 8 consecutive children x 32 c,
// all sharing one spatial (288 children / 8 = 36 blocks per spatial, exact).
// p_hat = exp(G - sum((vE-mu)^2)), coalesced store; D accumulated by atomics.
__global__ __launch_bounds__(256, 4) void estep_kernel(
    const float* __restrict__ Wt, const float* __restrict__ posT,
    float* __restrict__ p_hat, float* __restrict__ Dbuf,
    const float* __restrict__ mu_arr, const float* __restrict__ G_arr) {
  __shared__ float smu[32 * 20];   // stride 20: conflict-free b128
  __shared__ float sG[32];

  const int gp = blockIdx.x * 256 + threadIdx.x;   // 2654208 = 10368*256
  const int c = gp & 31;
  const int childg = gp >> 5;
  const int spatial = childg / 288;
  const int chl = childg - spatial * 288;           // = ij*32 + o
  const int o = chl & 31, ij = chl >> 5;
  int t = spatial;
  const int y = t % 6; t /= 6;
  const int xx = t % 6;
  const int n = t / 6;

  {
    const float* mb = mu_arr + (size_t)spatial * 512;
    for (int k = threadIdx.x; k < 512; k += 256) {
      int cc = k >> 4, d = k & 15;
      smu[cc * 20 + d] = mb[k];
    }
    if (threadIdx.x < 32) sG[threadIdx.x] = G_arr[spatial * 32 + threadIdx.x];
  }
  __syncthreads();

  const int i = ij / 3, j = ij - i * 3;
  const int i2 = (i == 0) ? 0 : 3 - i;   // kperm = {0,2,1}
  const int j2 = (j == 0) ? 0 : 3 - j;
  const int row2 = 2 * xx + i2, col2 = 2 * y + j2;

  float P[16];
  load16(posT + ((size_t)((n * 32 + o) * 169) + row2 * 13 + col2) * 16, P);
  float Wm[16];
  load16(Wt + ((size_t)((i2 * 3 + j2) * 32 + o) * 32 + c) * 16, Wm);
  float mu[16];
  load16(smu + c * 20, mu);

  float sumsq = 0.f;
#pragma unroll
  for (int p = 0; p < 4; ++p)
#pragma unroll
    for (int r = 0; r < 4; ++r) {
      float v = Wm[p * 4 + 0] * P[0 + r] + Wm[p * 4 + 1] * P[4 + r] +
                Wm[p * 4 + 2] * P[8 + r] + Wm[p * 4 + 3] * P[12 + r];
      float dv = v - mu[p * 4 + r];
      sumsq = fmaf(dv, dv, sumsq);
    }

  const float ph = __expf(sG[c] - sumsq);
  p_hat[((size_t)spatial * 288 + chl) * 32 + c] = ph;   // coalesced

  float T = ph;
#pragma unroll
  for (int m = 16; m >= 1; m >>= 1) T += __shfl_xor(T, m, 32);
  if (c == 0)
    atomicAdd(&Dbuf[((n * 32 + o) * 13 + 2 * xx + i) * 13 + 2 * y + j], T);
}

extern "C" void kernel_launch(void* const* d_in, const int* in_sizes, int n_in,
                              void* d_out, int out_size, void* d_ws,
                              size_t ws_size, hipStream_t stream) {
  const float* x   = (const float*)d_in[0];
  const float* Wt  = (const float*)d_in[1];
  const float* bv  = (const float*)d_in[2];
  const float* ba  = (const float*)d_in[3];
  const float* lam = (const float*)d_in[4];
  float* out = (float*)d_out;
  float* ws = (float*)d_ws;

  float* p_hat = ws + OFF_PHAT;
  float* Dbuf  = ws + OFF_D;
  float* mu    = ws + OFF_MU;
  float* G     = ws + OFF_G;
  float* E     = ws + OFF_E;
  float* posT  = ws + OFF_POST;

  (void)in_sizes; (void)n_in; (void)out_size; (void)ws_size;

  prep_kernel<<<2704, 256, 0, stream>>>(x, posT);
  e0_kernel<<<169, 256, 0, stream>>>(x, E);
  hipMemsetAsync(Dbuf, 0, 43264 * sizeof(float), stream);

  // iter 0
  mstep_kernel<<<2304, 256, 0, stream>>>(Wt, posT, p_hat, E, mu, G, bv, ba, lam,
                                         out, 0);
  estep_kernel<<<10368, 256, 0, stream>>>(Wt, posT, p_hat, Dbuf, mu, G);
  recip_kernel<<<169, 256, 0, stream>>>(x, Dbuf, E);
  hipMemsetAsync(Dbuf, 0, 43264 * sizeof(float), stream);
  // iter 1
  mstep_kernel<<<2304, 256, 0, stream>>>(Wt, posT, p_hat, E, mu, G, bv, ba, lam,
                                         out, 1);
  estep_kernel<<<10368, 256, 0, stream>>>(Wt, posT, p_hat, Dbuf, mu, G);
  recip_kernel<<<169, 256, 0, stream>>>(x, Dbuf, E);
  // iter 2 (final, writes output)
  mstep_kernel<<<2304, 256, 0, stream>>>(Wt, posT, p_hat, E, mu, G, bv, ba, lam,
                                         out, 2);
}

// Round 3
// 298.889 us; speedup vs baseline: 1.1394x; 1.1394x over previous
//
#include <hip/hip_runtime.h>

// ---------------------------------------------------------------------------
// ConvCaps (EM routing): b=8, B=32, C=32, K=3, stride=2, Win=13, Wout=6, 3 iters
// x: (8, 544, 13, 13) f32   [pose 512ch = (q,r,o), act 32ch]
// W: (3,3,32,32,4,4) f32    [i,j,o,c,p,q]
// out: (8, 544, 6, 6) f32
// vote[d = p*4+r] = sum_q W[i,j,o,c,p,q] * pose[n,q,r,o,2x+i,2y+j]
// child index ch = ij*32 + o
// p_hat layout: [spatial][c][ch]  -> coalesced mstep reads AND estep stores
// ---------------------------------------------------------------------------

#define NCHILD 288

// workspace layout (floats)
#define OFF_PHAT 0            // 2654208  ([spatial][c][ch])
#define OFF_D    2654208      // 43264 = 8*32*169
#define OFF_MU   2697472      // 9216*16
#define OFF_G    2844928      // 9216
#define OFF_POST 2854144      // 692224 = 8*32*169*16
// total 3546368 floats = 14.19 MB

__device__ __forceinline__ float wred64(float v) {
#pragma unroll
  for (int m = 32; m >= 1; m >>= 1) v += __shfl_xor(v, m, 64);
  return v;
}

__device__ __forceinline__ void load16(const float* __restrict__ p, float* dst) {
  const float4* p4 = (const float4*)p;
  float4 a = p4[0], b = p4[1], c = p4[2], d = p4[3];
  dst[0]=a.x; dst[1]=a.y; dst[2]=a.z; dst[3]=a.w;
  dst[4]=b.x; dst[5]=b.y; dst[6]=b.z; dst[7]=b.w;
  dst[8]=c.x; dst[9]=c.y; dst[10]=c.z; dst[11]=c.w;
  dst[12]=d.x; dst[13]=d.y; dst[14]=d.z; dst[15]=d.w;
}

// transpose pose: x[n, (q*4+r)*32+o, pix] -> posT[((n*32+o)*169+pix)*16 + d]
__global__ __launch_bounds__(256) void prep_kernel(const float* __restrict__ x,
                                                   float* __restrict__ posT) {
  int tid = blockIdx.x * 256 + threadIdx.x;   // 692224 = 2704*256
  int pix = tid % 169; int t = tid / 169;
  int o = t & 31; t >>= 5;
  int d = t & 15; int n = t >> 4;
  float v = x[((size_t)n * 544 + d * 32 + o) * 169 + pix];
  posT[((size_t)(n * 32 + o) * 169 + pix) * 16 + d] = v;
}

// M-step: block = 256 threads = 4 waves = 4 parents sharing one spatial (n,x,y).
// Pose patch (288 x 16) and rhat-scale E = a/D (or a/1152) staged in LDS.
// mode 0: rhat = E;  mode 1: rhat = p_hat*E;  mode 2: same + write final out
__global__ __launch_bounds__(256, 2) void mstep_kernel(
    const float* __restrict__ x, const float* __restrict__ Wt,
    const float* __restrict__ posT,
    const float* __restrict__ p_hatT, const float* __restrict__ Dbuf,
    float* __restrict__ mu_out, float* __restrict__ G_out,
    const float* __restrict__ beta_v, const float* __restrict__ beta_a,
    const float* __restrict__ lambda_, float* __restrict__ out, int mode) {
  __shared__ float sP[288 * 20];   // stride 20 floats: conflict-free b128
  __shared__ float sE[288];

  const int wave = threadIdx.x >> 6;
  const int lane = threadIdx.x & 63;
  const int pid = blockIdx.x * 4 + wave;   // = spatial*32 + c
  const int c = pid & 31;
  const int spatial = pid >> 5;
  int t = spatial;
  const int y = t % 6; t /= 6;
  const int xx = t % 6;
  const int n = t / 6;

  // cooperative stage: 288 children * 4 float4 quads of pose
  for (int task = threadIdx.x; task < 1152; task += 256) {
    int ch = task >> 2, q = task & 3;
    int o = ch & 31, ij = ch >> 5;
    int i = ij / 3, j = ij - i * 3;
    int row = 2 * xx + i, col = 2 * y + j;
    float4 v = *(const float4*)(posT +
        ((size_t)((n * 32 + o) * 169) + row * 13 + col) * 16 + q * 4);
    *(float4*)(sP + ch * 20 + q * 4) = v;
  }
  for (int task = threadIdx.x; task < 288; task += 256) {
    int o = task & 31, ij = task >> 5;
    int i = ij / 3, j = ij - i * 3;
    int pix = (2 * xx + i) * 13 + (2 * y + j);
    float a = x[(size_t)n * 91936 + 86528 + o * 169 + pix];
    if (mode == 0) sE[task] = a * (1.0f / 1152.0f);
    else           sE[task] = a / Dbuf[(n * 32 + o) * 169 + pix];
  }
  __syncthreads();

  float sum_r = 0.f;
  float sv[16], sq[16];
#pragma unroll
  for (int d = 0; d < 16; ++d) { sv[d] = 0.f; sq[d] = 0.f; }

  const float* phb = p_hatT + (size_t)spatial * 9216 + (size_t)c * 288;

#pragma unroll
  for (int k = 0; k < 5; ++k) {
    int ch = lane + 64 * k;
    const bool active = (ch < NCHILD);
    const int chm = active ? ch : 0;

    float P[16];
    load16(sP + chm * 20, P);
    float Wm[16];
    load16(Wt + (size_t)chm * 512 + c * 16, Wm);

    float rhat;
    if (mode == 0) rhat = sE[chm];
    else           rhat = phb[chm] * sE[chm];   // coalesced 4B/lane
    if (!active) rhat = 0.f;
    sum_r += rhat;
#pragma unroll
    for (int p = 0; p < 4; ++p)
#pragma unroll
      for (int r = 0; r < 4; ++r) {
        float v = Wm[p * 4 + 0] * P[0 + r] + Wm[p * 4 + 1] * P[4 + r] +
                  Wm[p * 4 + 2] * P[8 + r] + Wm[p * 4 + 3] * P[12 + r];
        sv[p * 4 + r] = fmaf(rhat, v, sv[p * 4 + r]);
        sq[p * 4 + r] = fmaf(rhat * v, v, sq[p * 4 + r]);
      }
  }

  sum_r = wred64(sum_r);
  const float inv_sr = 1.0f / sum_r;
  float mu[16], sig[16];
#pragma unroll
  for (int d = 0; d < 16; ++d) {
    float s1 = wred64(sv[d]);
    float s2 = wred64(sq[d]);
    float m = s1 * inv_sr;
    mu[d] = m;
    sig[d] = fmaxf(s2 * inv_sr - m * m, 1e-30f);
  }

  const float bv = beta_v[0], ba = beta_a[0], lam = lambda_[0];
  float lsum = 0.f;
#pragma unroll
  for (int d = 0; d < 16; ++d) lsum += __logf(sig[d]);
  const float cost = (16.f * bv + lsum) * sum_r;
  const float z = lam * (ba - cost);
  const float aout = 1.0f / (1.0f + __expf(-z));

  if (lane == 0) {
    if (mode == 2) {
      float* ob = out + (size_t)(n * 544 + c * 16) * 36 + xx * 6 + y;
#pragma unroll
      for (int d = 0; d < 16; ++d) ob[d * 36] = mu[d];
      out[(size_t)(n * 544 + 512 + c) * 36 + xx * 6 + y] = aout;
    } else {
      float* mb = mu_out + (size_t)pid * 16;
#pragma unroll
      for (int d = 0; d < 16; ++d) mb[d] = mu[d];
      const float S = lsum + 16.f * 1.8378770664093453f;  // + 16*log(2*pi)
      G_out[pid] = __logf(aout) - 0.5f * S;
    }
  }
}

// E-step: block = 256 threads = (8 c) x (32 o) for one (spatial, ij).
// Grid = 288 spatial * 4 c_grp * 9 ij = 10368 blocks.
// Stores p_hatT[spatial][c][ij*32+o]: contiguous 128B per half-wave.
// D partials: shfl over c-pair + LDS reduce over 4 waves -> 1 atomic per o.
__global__ __launch_bounds__(256, 2) void estep_kernel(
    const float* __restrict__ Wt, const float* __restrict__ posT,
    float* __restrict__ p_hatT, float* __restrict__ Dbuf,
    const float* __restrict__ mu_arr, const float* __restrict__ G_arr) {
  __shared__ float sD[128];

  const int b = blockIdx.x;
  const int spatial = b / 36;
  const int rem = b - spatial * 36;
  const int c_grp = rem / 9;            // 0..3
  const int ij = rem - c_grp * 9;       // 0..8
  const int o = threadIdx.x & 31;
  const int c = c_grp * 8 + (threadIdx.x >> 5);
  int t = spatial;
  const int y = t % 6; t /= 6;
  const int xx = t % 6;
  const int n = t / 6;

  const int i = ij / 3, j = ij - i * 3;
  const int i2 = (i == 0) ? 0 : 3 - i;   // kperm = {0,2,1}
  const int j2 = (j == 0) ? 0 : 3 - j;
  const int row2 = 2 * xx + i2, col2 = 2 * y + j2;

  float P[16];
  load16(posT + ((size_t)((n * 32 + o) * 169) + row2 * 13 + col2) * 16, P);
  float Wm[16];
  load16(Wt + ((size_t)((i2 * 3 + j2) * 32 + o) * 32 + c) * 16, Wm);
  float mu[16];
  load16(mu_arr + ((size_t)spatial * 32 + c) * 16, mu);

  float sumsq = 0.f;
#pragma unroll
  for (int p = 0; p < 4; ++p)
#pragma unroll
    for (int r = 0; r < 4; ++r) {
      float v = Wm[p * 4 + 0] * P[0 + r] + Wm[p * 4 + 1] * P[4 + r] +
                Wm[p * 4 + 2] * P[8 + r] + Wm[p * 4 + 3] * P[12 + r];
      float dv = v - mu[p * 4 + r];
      sumsq = fmaf(dv, dv, sumsq);
    }

  const float ph = __expf(G_arr[spatial * 32 + c] - sumsq);
  p_hatT[((size_t)spatial * 32 + c) * 288 + ij * 32 + o] = ph;   // coalesced

  float T = ph + __shfl_xor(ph, 32, 64);    // sum c-pair within wave
  const int wv = threadIdx.x >> 6;
  if ((threadIdx.x & 63) < 32) sD[wv * 32 + o] = T;
  __syncthreads();
  if (threadIdx.x < 32) {
    float s = sD[threadIdx.x] + sD[32 + threadIdx.x] +
              sD[64 + threadIdx.x] + sD[96 + threadIdx.x];
    atomicAdd(&Dbuf[(n * 32 + threadIdx.x) * 169 + (2 * xx + i) * 13 + 2 * y + j], s);
  }
}

extern "C" void kernel_launch(void* const* d_in, const int* in_sizes, int n_in,
                              void* d_out, int out_size, void* d_ws,
                              size_t ws_size, hipStream_t stream) {
  const float* x   = (const float*)d_in[0];
  const float* Wt  = (const float*)d_in[1];
  const float* bv  = (const float*)d_in[2];
  const float* ba  = (const float*)d_in[3];
  const float* lam = (const float*)d_in[4];
  float* out = (float*)d_out;
  float* ws = (float*)d_ws;

  float* p_hatT = ws + OFF_PHAT;
  float* Dbuf   = ws + OFF_D;
  float* mu     = ws + OFF_MU;
  float* G      = ws + OFF_G;
  float* posT   = ws + OFF_POST;

  (void)in_sizes; (void)n_in; (void)out_size; (void)ws_size;

  prep_kernel<<<2704, 256, 0, stream>>>(x, posT);
  hipMemsetAsync(Dbuf, 0, 43264 * sizeof(float), stream);

  // iter 0
  mstep_kernel<<<2304, 256, 0, stream>>>(x, Wt, posT, p_hatT, Dbuf, mu, G,
                                         bv, ba, lam, out, 0);
  estep_kernel<<<10368, 256, 0, stream>>>(Wt, posT, p_hatT, Dbuf, mu, G);
  // iter 1 (reads D from estep 1, then D is re-zeroed for estep 2)
  mstep_kernel<<<2304, 256, 0, stream>>>(x, Wt, posT, p_hatT, Dbuf, mu, G,
                                         bv, ba, lam, out, 1);
  hipMemsetAsync(Dbuf, 0, 43264 * sizeof(float), stream);
  estep_kernel<<<10368, 256, 0, stream>>>(Wt, posT, p_hatT, Dbuf, mu, G);
  // iter 2 (final, writes output)
  mstep_kernel<<<2304, 256, 0, stream>>>(x, Wt, posT, p_hatT, Dbuf, mu, G,
                                         bv, ba, lam, out, 2);
}